// Round 3
// baseline (123.596 us; speedup 1.0000x reference)
//
#include <hip/hip_runtime.h>
#include <math.h>

// y[b,f,t] = | x[t] - C_f*w_f * S[t] |,  S[t] = sum_{j=0}^{497} a^j x[t-1-j] (edge-padded)
// S[t+1] = a*S[t] + x[t] - a^498 * x[t-498]
//
// R2: DPP weighted wave scan (row_shr 1/2/4/8 + row_bcast15/31) replaces the
// ds_permute shuffle scan; exclusive term via (G - q)/r; carry via v_readlane.
// ROUND=512 (8 samples/lane). Zero LDS-pipe ops in the main loop.

constexpr int T      = 8000;
constexpr int F      = 64;
constexpr int B      = 32;
constexpr int KM1    = 498;
constexpr int NSEG   = 4;
constexpr int SEGLEN = T / NSEG;              // 2000
constexpr int ROUND  = 512;                   // 8 per lane
constexpr int NFULL  = SEGLEN / ROUND;        // 3 full rounds
constexpr int TAILN  = SEGLEN - NFULL * ROUND; // 464 = 8*58

#define DPP_F(x, ctrl, rm) \
  __builtin_bit_cast(float, __builtin_amdgcn_update_dpp(0, __builtin_bit_cast(int, (x)), (ctrl), (rm), 0xf, false))

__device__ __forceinline__ double dpow(double b, int e) {
    double r = 1.0, p = b;
    while (e) { if (e & 1) r *= p; p *= p; e >>= 1; }
    return r;
}

__global__ __launch_bounds__(256) void willmore_scan_kernel(
    const float* __restrict__ x, const float* __restrict__ a,
    const float* __restrict__ w, float* __restrict__ out)
{
    const int row  = blockIdx.x;                // b*F + f
    const int seg  = threadIdx.x >> 6;          // 0..3
    const int lane = threadIdx.x & 63;
    const int f = row % F;

    const float* xr   = x   + (size_t)row * T;
    float*       orow = out + (size_t)row * T;

    // --- per-row constants (double precompute) ---
    const double ad     = (double)a[f];
    const double a498d  = dpow(ad, KM1);
    const double sumgeo = (1.0 - a498d) / (1.0 - ad);
    const double r_d    = dpow(ad, 8);            // scan ratio a^8
    const float  af     = (float)ad;
    const float  na498  = (float)(-a498d);
    const float  g      = (float)(1.0 / sumgeo) * w[f];
    const float  r1     = (float)r_d;
    const float  r2     = (float)(r_d * r_d);
    const float  r4     = (float)dpow(r_d, 4);
    const float  r8     = (float)dpow(r_d, 8);
    const float  a512   = (float)dpow(r_d, 64);
    const float  inv_r  = (float)(1.0 / r_d);
    const float  alane  = (float)dpow(r_d, lane);             // a^(8*lane)
    const float  wA     = (float)dpow(r_d, (lane & 15) + 1);  // bcast15 weight
    const float  wB     = (float)dpow(r_d, (lane & 31) + 1);  // bcast31 weight

    const int t0 = seg * SEGLEN;

    // --- warm-up: S = S[t0] = sum_{j=0}^{497} a^j x[t0-1-j] ---
    float S;
    if (t0 == 0) {
        S = xr[0] * (float)sumgeo;
    } else {
        const int base = t0 - 512 + 8 * lane;   // 32B-aligned
        const float4 v0 = *(const float4*)(xr + base);
        const float4 v1 = *(const float4*)(xr + base + 4);
        float xs[8] = {v0.x, v0.y, v0.z, v0.w, v1.x, v1.y, v1.z, v1.w};
        #pragma unroll
        for (int i = 0; i < 8; ++i) { if (511 - 8 * lane - i >= KM1) xs[i] = 0.0f; }
        float h = xs[0];
        #pragma unroll
        for (int i = 1; i < 8; ++i) h = fmaf(h, af, xs[i]);
        float contrib = (float)dpow(ad, 504 - 8 * lane) * h;
        #pragma unroll
        for (int s = 1; s < 64; s <<= 1) contrib += __shfl_xor(contrib, s, 64);
        S = contrib;
    }

    // --- 3 full rounds + 464-sample tail ---
    #pragma unroll
    for (int rnd = 0; rnd <= NFULL; ++rnd) {
        const bool last = (rnd == NFULL);
        const int tR = t0 + rnd * ROUND;
        int tb = tR + 8 * lane;
        if (last) tb = min(tb, T - 8);          // only bites for seg 3 tail lanes

        const float4 v0 = *(const float4*)(xr + tb);
        const float4 v1 = *(const float4*)(xr + tb + 4);
        const float xv[8] = {v0.x, v0.y, v0.z, v0.w, v1.x, v1.y, v1.z, v1.w};

        const int lg = tb - KM1;                // even -> 8B-aligned
        float lv[8];
        if (t0 == 0 && rnd == 0) {
            #pragma unroll
            for (int i = 0; i < 8; ++i) lv[i] = xr[max(lg + i, 0)];
        } else {
            const float2 p0 = *(const float2*)(xr + lg);
            const float2 p1 = *(const float2*)(xr + lg + 2);
            const float2 p2 = *(const float2*)(xr + lg + 4);
            const float2 p3 = *(const float2*)(xr + lg + 6);
            lv[0]=p0.x; lv[1]=p0.y; lv[2]=p1.x; lv[3]=p1.y;
            lv[4]=p2.x; lv[5]=p2.y; lv[6]=p3.x; lv[7]=p3.y;
        }

        float u[8];
        #pragma unroll
        for (int i = 0; i < 8; ++i) u[i] = fmaf(na498, lv[i], xv[i]);

        // lane aggregate q = sum_i a^(7-i) u_i
        float q = u[0];
        #pragma unroll
        for (int i = 1; i < 8; ++i) q = fmaf(q, af, u[i]);

        // DPP weighted inclusive scan across lanes, ratio r = a^8
        float G = q;
        G = fmaf(r1, DPP_F(G, 0x111, 0xf), G);   // row_shr:1
        G = fmaf(r2, DPP_F(G, 0x112, 0xf), G);   // row_shr:2
        G = fmaf(r4, DPP_F(G, 0x114, 0xf), G);   // row_shr:4
        G = fmaf(r8, DPP_F(G, 0x118, 0xf), G);   // row_shr:8
        G = fmaf(wA, DPP_F(G, 0x142, 0xa), G);   // row_bcast15 -> rows 1,3
        G = fmaf(wB, DPP_F(G, 0x143, 0xc), G);   // row_bcast31 -> rows 2,3

        // exclusive prefix for this lane: G_{l-1} = (G - q)/r  (exact 0 at lane 0)
        const float E = (G - q) * inv_r;

        // per-sample states + outputs
        float s = fmaf(alane, S, E);
        float y[8];
        #pragma unroll
        for (int i = 0; i < 8; ++i) {
            y[i] = fabsf(fmaf(-g, s, xv[i]));
            s = fmaf(af, s, u[i]);
        }

        if (!last || lane < TAILN / 8) {
            *(float4*)(orow + tb)     = make_float4(y[0], y[1], y[2], y[3]);
            *(float4*)(orow + tb + 4) = make_float4(y[4], y[5], y[6], y[7]);
        }

        if (!last) {
            const float G63 = __builtin_bit_cast(float,
                __builtin_amdgcn_readlane(__builtin_bit_cast(int, G), 63));
            S = fmaf(a512, S, G63);              // carry: S[tR+512]
        }
    }
}

extern "C" void kernel_launch(void* const* d_in, const int* in_sizes, int n_in,
                              void* d_out, int out_size, void* d_ws, size_t ws_size,
                              hipStream_t stream) {
    const float* x = (const float*)d_in[0];
    const float* a = (const float*)d_in[1];
    const float* w = (const float*)d_in[2];
    float* out = (float*)d_out;

    const int blocks = B * F;   // one block per row; 4 waves = 4 segments
    hipLaunchKernelGGL(willmore_scan_kernel, dim3(blocks), dim3(256), 0, stream,
                       x, a, w, out);
}

// Round 4
// 115.966 us; speedup vs baseline: 1.0658x; 1.0658x over previous
//
#include <hip/hip_runtime.h>
#include <math.h>

// y[b,f,t] = | x[t] - C_f*w_f * S[t] |,  S[t] = sum_{j=0}^{497} a^j x[t-1-j] (edge-padded)
//
// R3: fully chunk-parallel. One wave = one 512-sample chunk, self-contained:
// warm-up S[t0] reduced from the preceding 512 samples (also the lag stream,
// so its loads are L1 hits). Zero inter-round dependencies -> each wave has
// ONE load->compute->store chain; 32768 waves give the CU plenty to overlap.
// (R2 lesson: DPP-vs-shuffle was irrelevant; serial rounds per wave were the cost.)

constexpr int T     = 8000;
constexpr int F     = 64;
constexpr int B     = 32;
constexpr int KM1   = 498;
constexpr int CHUNK = 512;                       // samples per wave (8/lane)
constexpr int CPR   = (T + CHUNK - 1) / CHUNK;   // 16 chunks per row (last = 320)

#define DPP_F(x, ctrl, rm) \
  __builtin_bit_cast(float, __builtin_amdgcn_update_dpp(0, __builtin_bit_cast(int, (x)), (ctrl), (rm), 0xf, false))

__device__ __forceinline__ double dpow(double b, int e) {
    double r = 1.0, p = b;
    while (e) { if (e & 1) r *= p; p *= p; e >>= 1; }
    return r;
}

// branch-free float base^e, e in [0, 512)
__device__ __forceinline__ float powi(float base, int e) {
    float r = 1.0f, p = base;
    #pragma unroll
    for (int b = 0; b < 9; ++b) { r = (e & (1 << b)) ? r * p : r; p *= p; }
    return r;
}

__global__ __launch_bounds__(256) void willmore_scan_kernel(
    const float* __restrict__ x, const float* __restrict__ a,
    const float* __restrict__ w, float* __restrict__ out)
{
    const int wid   = blockIdx.x * 4 + (threadIdx.x >> 6);
    const int lane  = threadIdx.x & 63;
    const int row   = wid >> 4;          // b*F + f  (consecutive waves = same row)
    const int chunk = wid & (CPR - 1);
    const int f     = row % F;

    const float* xr   = x   + (size_t)row * T;
    float*       orow = out + (size_t)row * T;

    // --- per-row constants ---
    const double ad     = (double)a[f];
    const double a498d  = dpow(ad, KM1);
    const double sumgeo = (1.0 - a498d) / (1.0 - ad);
    const double r_d    = dpow(ad, 8);
    const float  af     = (float)ad;
    const float  na498  = (float)(-a498d);
    const float  g      = (float)(1.0 / sumgeo) * w[f];
    const float  r1     = (float)r_d;
    const float  r2     = (float)(r_d * r_d);
    const float  r4     = (float)dpow(r_d, 4);
    const float  r8     = (float)dpow(r_d, 8);
    const float  inv_r  = (float)(1.0 / r_d);
    const float  alane  = powi(af, 8 * lane);                  // a^(8*lane)
    const float  wA     = powi(af, 8 * ((lane & 15) + 1));     // bcast15 weight
    const float  wB     = powi(af, 8 * ((lane & 31) + 1));     // bcast31 weight

    const int t0   = chunk * CHUNK;
    const int tb_u = t0 + 8 * lane;          // unclamped output base
    const int tb   = min(tb_u, T - 8);       // clamp bites only in chunk 15

    // ---- issue ALL loads up front (one latency round-trip per wave) ----
    const float4 m0 = *(const float4*)(xr + tb);
    const float4 m1 = *(const float4*)(xr + tb + 4);

    float ws8[8];                            // warm-up window [t0-512, t0)
    float lv[8];                             // lag window x[tb-498 .. tb-491]
    const int lg = tb - KM1;
    if (chunk > 0) {
        const int wb = t0 - CHUNK + 8 * lane;
        const float4 w0 = *(const float4*)(xr + wb);
        const float4 w1 = *(const float4*)(xr + wb + 4);
        ws8[0]=w0.x; ws8[1]=w0.y; ws8[2]=w0.z; ws8[3]=w0.w;
        ws8[4]=w1.x; ws8[5]=w1.y; ws8[6]=w1.z; ws8[7]=w1.w;
        const float2 p0 = *(const float2*)(xr + lg);       // lg even -> 8B aligned
        const float2 p1 = *(const float2*)(xr + lg + 2);
        const float2 p2 = *(const float2*)(xr + lg + 4);
        const float2 p3 = *(const float2*)(xr + lg + 6);
        lv[0]=p0.x; lv[1]=p0.y; lv[2]=p1.x; lv[3]=p1.y;
        lv[4]=p2.x; lv[5]=p2.y; lv[6]=p3.x; lv[7]=p3.y;
    } else {
        #pragma unroll
        for (int i = 0; i < 8; ++i) lv[i] = xr[max(lg + i, 0)];
    }

    // ---- warm-up: S = S[t0] = sum_{j=0}^{497} a^j x[t0-1-j] ----
    float S;
    if (chunk == 0) {
        S = m0.x;                            // lane-0 value not needed; recompute:
        S = xr[0] * (float)sumgeo;           // uniform (L1 hit)
    } else {
        // idx = t0-512+8*lane+i has j = 511-8*lane-i; drop j>497 (8*lane+i<14)
        #pragma unroll
        for (int i = 0; i < 8; ++i) { if (8 * lane + i < 14) ws8[i] = 0.0f; }
        float h = ws8[0];
        #pragma unroll
        for (int i = 1; i < 8; ++i) h = fmaf(h, af, ws8[i]);
        float contrib = powi(af, 504 - 8 * lane) * h;
        #pragma unroll
        for (int s = 1; s < 64; s <<= 1) contrib += __shfl_xor(contrib, s, 64);
        S = contrib;
    }

    // ---- main: u, lane aggregate, DPP weighted scan (ratio a^8) ----
    const float xv[8] = {m0.x, m0.y, m0.z, m0.w, m1.x, m1.y, m1.z, m1.w};
    float u[8];
    #pragma unroll
    for (int i = 0; i < 8; ++i) u[i] = fmaf(na498, lv[i], xv[i]);

    float q = u[0];
    #pragma unroll
    for (int i = 1; i < 8; ++i) q = fmaf(q, af, u[i]);

    float G = q;
    G = fmaf(r1, DPP_F(G, 0x111, 0xf), G);   // row_shr:1
    G = fmaf(r2, DPP_F(G, 0x112, 0xf), G);   // row_shr:2
    G = fmaf(r4, DPP_F(G, 0x114, 0xf), G);   // row_shr:4
    G = fmaf(r8, DPP_F(G, 0x118, 0xf), G);   // row_shr:8
    G = fmaf(wA, DPP_F(G, 0x142, 0xa), G);   // row_bcast15 -> rows 1,3
    G = fmaf(wB, DPP_F(G, 0x143, 0xc), G);   // row_bcast31 -> rows 2,3

    const float E = (G - q) * inv_r;         // exclusive prefix (exact 0 at lane 0)

    float s = fmaf(alane, S, E);             // S[t0 + 8*lane]
    float y[8];
    #pragma unroll
    for (int i = 0; i < 8; ++i) {
        y[i] = fabsf(fmaf(-g, s, xv[i]));
        s = fmaf(af, s, u[i]);
    }

    if (tb_u <= T - 8) {
        *(float4*)(orow + tb)     = make_float4(y[0], y[1], y[2], y[3]);
        *(float4*)(orow + tb + 4) = make_float4(y[4], y[5], y[6], y[7]);
    }
}

extern "C" void kernel_launch(void* const* d_in, const int* in_sizes, int n_in,
                              void* d_out, int out_size, void* d_ws, size_t ws_size,
                              hipStream_t stream) {
    const float* x = (const float*)d_in[0];
    const float* a = (const float*)d_in[1];
    const float* w = (const float*)d_in[2];
    float* out = (float*)d_out;

    const int blocks = B * F * CPR / 4;      // 8192 blocks x 4 waves = 32768 chunks
    hipLaunchKernelGGL(willmore_scan_kernel, dim3(blocks), dim3(256), 0, stream,
                       x, a, w, out);
}